// Round 1
// baseline (1668.929 us; speedup 1.0000x reference)
//
#include <hip/hip_runtime.h>
#include <hip/hip_bf16.h>
#include <math.h>

// Problem constants
#define Bc  32
#define Nn  512
#define Dd  256
#define Hh  8
#define HDd 32
#define Ee  16384

// ---------------- graph prep ----------------

__global__ __launch_bounds__(256) void k_init(int* count){
  int i = blockIdx.x*256 + threadIdx.x;
  if (i < Nn) count[i] = 0;
}

__global__ __launch_bounds__(256) void k_count(const int* __restrict__ ei, int* __restrict__ count){
  int e = blockIdx.x*256 + threadIdx.x;
  if (e < Ee){
    int d = ei[Ee + e];        // dst row of edge_index [2,E]
    atomicAdd(&count[d], 1);
  }
}

// single block of 512: dinv = 1/sqrt(1+count); exclusive scan count -> row_start, cursor
__global__ __launch_bounds__(512) void k_scan(const int* __restrict__ count, float* __restrict__ dinv,
                                              int* __restrict__ row_start, int* __restrict__ cursor){
  __shared__ int tmp[512];
  int t = threadIdx.x;
  int c = count[t];
  tmp[t] = c;
  dinv[t] = 1.0f / sqrtf(1.0f + (float)c);   // deg includes self-loop
  __syncthreads();
  for (int off = 1; off < 512; off <<= 1){
    int add = (t >= off) ? tmp[t-off] : 0;
    __syncthreads();
    tmp[t] += add;
    __syncthreads();
  }
  int excl = tmp[t] - c;
  row_start[t] = excl;
  cursor[t]    = excl;
  if (t == 511) row_start[512] = tmp[511];
}

__global__ __launch_bounds__(256) void k_fill(const int* __restrict__ ei, const float* __restrict__ dinv,
                                              int* __restrict__ cursor, int* __restrict__ csr_src,
                                              float* __restrict__ csr_w){
  int e = blockIdx.x*256 + threadIdx.x;
  if (e < Ee){
    int s = ei[e];
    int d = ei[Ee + e];
    int pos = atomicAdd(&cursor[d], 1);
    csr_src[pos] = s;
    csr_w[pos]   = dinv[s] * dinv[d];
  }
}

// ---------------- GCN aggregation: out[b,n,:] = dinv[n]^2 * x[b,n,:] + sum_e w_e * x[b,src_e,:]
__global__ __launch_bounds__(256) void k_agg(const float* __restrict__ x, const float* __restrict__ dinv,
                                             const int* __restrict__ row_start, const int* __restrict__ csr_src,
                                             const float* __restrict__ csr_w, float* __restrict__ out){
  int bn = blockIdx.x;          // b*512 + n
  int n  = bn & (Nn-1);
  int b  = bn >> 9;
  int d  = threadIdx.x;         // 0..255
  const float* xb = x + (size_t)b*Nn*Dd;
  float acc = dinv[n]*dinv[n] * xb[n*Dd + d];
  int s0 = row_start[n], s1 = row_start[n+1];
  for (int j = s0; j < s1; j++){
    int   s = csr_src[j];
    float w = csr_w[j];
    acc += w * xb[s*Dd + d];
  }
  out[(size_t)bn*Dd + d] = acc;
}

// ---------------- GEMM: C[M=16384 x 256] = A * W + bias; optional [B,H,N,HD] remap
__global__ __launch_bounds__(256) void k_gemm(const float* __restrict__ A, const float* __restrict__ W,
                                              const float* __restrict__ bias, float* __restrict__ out,
                                              int qkv_layout){
  __shared__ float As[16][65];   // As[k][m]
  __shared__ float Bs[16][65];   // Bs[k][n]
  int t  = threadIdx.x;
  int m0 = blockIdx.x * 64;
  int n0 = blockIdx.y * 64;
  int ty = t >> 4, tx = t & 15;
  float acc[4][4] = {};
  for (int k0 = 0; k0 < Dd; k0 += 16){
    #pragma unroll
    for (int r = 0; r < 4; r++){
      int idx = t + r*256;
      int mm = idx >> 4, kk = idx & 15;
      As[kk][mm] = A[(size_t)(m0+mm)*Dd + k0 + kk];
    }
    #pragma unroll
    for (int r = 0; r < 4; r++){
      int idx = t + r*256;
      int kk = idx >> 6, nn = idx & 63;
      Bs[kk][nn] = W[(size_t)(k0+kk)*Dd + n0 + nn];
    }
    __syncthreads();
    #pragma unroll
    for (int kk = 0; kk < 16; kk++){
      float a[4], bb[4];
      #pragma unroll
      for (int u = 0; u < 4; u++) a[u]  = As[kk][ty*4+u];
      #pragma unroll
      for (int v = 0; v < 4; v++) bb[v] = Bs[kk][tx*4+v];
      #pragma unroll
      for (int u = 0; u < 4; u++)
        #pragma unroll
        for (int v = 0; v < 4; v++)
          acc[u][v] += a[u]*bb[v];
    }
    __syncthreads();
  }
  #pragma unroll
  for (int u = 0; u < 4; u++){
    int m = m0 + ty*4 + u;
    int b = m >> 9, n = m & (Nn-1);
    #pragma unroll
    for (int v = 0; v < 4; v++){
      int col = n0 + tx*4 + v;
      float val = acc[u][v] + bias[col];
      if (qkv_layout){
        int h = col >> 5, hd = col & 31;
        out[((((size_t)b*Hh + h)*Nn) + n)*HDd + hd] = val;
      } else {
        out[(size_t)m*Dd + col] = val;
      }
    }
  }
}

// ---------------- fused attention: block per (b,h, 16-query tile); exact 2-pass softmax in LDS
__global__ __launch_bounds__(256) void k_attn(const float* __restrict__ Qh, const float* __restrict__ Kh,
                                              const float* __restrict__ Vh, const int* __restrict__ mask,
                                              float* __restrict__ xout){
  int blk = blockIdx.x;
  int qt  = blk & 31;             // 32 q-tiles of 16 rows
  int bh  = blk >> 5;             // 0..255
  int b   = bh >> 3, h = bh & 7;
  const float* Qp = Qh + (size_t)bh*Nn*HDd;
  const float* Kp = Kh + (size_t)bh*Nn*HDd;
  const float* Vp = Vh + (size_t)bh*Nn*HDd;

  __shared__ float S[16][513];    // padded: breaks 16-way bank conflict at stride 512
  __shared__ float Qs[16][33];
  __shared__ float red[16][17];
  __shared__ float mrow[16], lrow[16];

  int t = threadIdx.x;
  // load Q tile
  for (int idx = t; idx < 16*32; idx += 256){
    int i = idx >> 5, d = idx & 31;
    Qs[i][d] = Qp[(qt*16 + i)*HDd + d];
  }
  __syncthreads();

  const float scale = 0.17677669529663687f;   // 1/sqrt(32)
  int i = t >> 4;    // q-row 0..15
  int l = t & 15;    // lane-of-16

  // phase 1: scores with mask
  #pragma unroll 4
  for (int j = 0; j < 32; j++){
    int k = j*16 + l;
    const float4* kr4 = (const float4*)(Kp + k*HDd);
    float acc = 0.f;
    #pragma unroll
    for (int dq = 0; dq < 8; dq++){
      float4 kv = kr4[dq];
      acc += Qs[i][dq*4+0]*kv.x + Qs[i][dq*4+1]*kv.y + Qs[i][dq*4+2]*kv.z + Qs[i][dq*4+3]*kv.w;
    }
    acc *= scale;
    if (mask[(qt*16 + i)*Nn + k] == 0) acc = -1e10f;
    S[i][k] = acc;
  }
  __syncthreads();

  // phase 2: row max, exp, sum
  float pm = -INFINITY;
  #pragma unroll
  for (int j = 0; j < 32; j++) pm = fmaxf(pm, S[i][j*16 + l]);
  red[i][l] = pm;
  __syncthreads();
  if (l == 0){
    float m = red[i][0];
    #pragma unroll
    for (int z = 1; z < 16; z++) m = fmaxf(m, red[i][z]);
    mrow[i] = m;
  }
  __syncthreads();
  float m = mrow[i];
  float ps = 0.f;
  #pragma unroll
  for (int j = 0; j < 32; j++){
    int k = j*16 + l;
    float e = __expf(S[i][k] - m);
    S[i][k] = e;
    ps += e;
  }
  red[i][l] = ps;
  __syncthreads();
  if (l == 0){
    float s = 0.f;
    #pragma unroll
    for (int z = 0; z < 16; z++) s += red[i][z];
    lrow[i] = s;
  }
  __syncthreads();

  // phase 3: O = P V, thread owns 2 (row, d) pairs
  #pragma unroll
  for (int rep = 0; rep < 2; rep++){
    int idx = t + rep*256;
    int i2 = idx >> 5, d = idx & 31;
    float inv = 1.0f / lrow[i2];
    float acc = 0.f;
    for (int k = 0; k < Nn; k++)
      acc += S[i2][k] * Vp[k*HDd + d];
    xout[(((size_t)b*Nn) + qt*16 + i2)*Dd + h*HDd + d] = acc * inv;
  }
}

// ---------------- launch ----------------
extern "C" void kernel_launch(void* const* d_in, const int* in_sizes, int n_in,
                              void* d_out, int out_size, void* d_ws, size_t ws_size,
                              hipStream_t stream){
  const float* query = (const float*)d_in[0];
  const float* key   = (const float*)d_in[1];
  const float* value = (const float*)d_in[2];
  const int*   ei    = (const int*)  d_in[3];
  const int*   mask  = (const int*)  d_in[4];
  const float* Wq = (const float*)d_in[5];
  const float* bq = (const float*)d_in[6];
  const float* Wk = (const float*)d_in[7];
  const float* bk = (const float*)d_in[8];
  const float* Wv = (const float*)d_in[9];
  const float* bv = (const float*)d_in[10];
  const float* Wo = (const float*)d_in[11];
  const float* bo = (const float*)d_in[12];

  char* ws = (char*)d_ws;
  size_t off = 0;
  auto alloc = [&](size_t bytes)->void*{
    void* p = ws + off;
    off = (off + bytes + 255) & ~(size_t)255;
    return p;
  };
  int*   count     = (int*)  alloc(Nn*4);
  int*   row_start = (int*)  alloc((Nn+1)*4);
  int*   cursor    = (int*)  alloc(Nn*4);
  float* dinv      = (float*)alloc(Nn*4);
  int*   csr_src   = (int*)  alloc((size_t)Ee*4);
  float* csr_w     = (float*)alloc((size_t)Ee*4);
  size_t tsz = (size_t)Bc*Nn*Dd*sizeof(float);
  float* aggbuf = (float*)alloc(tsz);
  float* Qh     = (float*)alloc(tsz);
  float* Kh     = (float*)alloc(tsz);
  float* Vh     = (float*)alloc(tsz);
  float* xbuf   = (float*)alloc(tsz);

  k_init <<<2, 256, 0, stream>>>(count);
  k_count<<<Ee/256, 256, 0, stream>>>(ei, count);
  k_scan <<<1, 512, 0, stream>>>(count, dinv, row_start, cursor);
  k_fill <<<Ee/256, 256, 0, stream>>>(ei, dinv, cursor, csr_src, csr_w);

  dim3 gg(Bc*Nn/64, Dd/64);   // (256, 4)

  k_agg <<<Bc*Nn, 256, 0, stream>>>(query, dinv, row_start, csr_src, csr_w, aggbuf);
  k_gemm<<<gg, 256, 0, stream>>>(aggbuf, Wq, bq, Qh, 1);
  k_agg <<<Bc*Nn, 256, 0, stream>>>(key, dinv, row_start, csr_src, csr_w, aggbuf);
  k_gemm<<<gg, 256, 0, stream>>>(aggbuf, Wk, bk, Kh, 1);
  k_agg <<<Bc*Nn, 256, 0, stream>>>(value, dinv, row_start, csr_src, csr_w, aggbuf);
  k_gemm<<<gg, 256, 0, stream>>>(aggbuf, Wv, bv, Vh, 1);

  k_attn<<<Bc*Hh*32, 256, 0, stream>>>(Qh, Kh, Vh, mask, xbuf);

  k_gemm<<<gg, 256, 0, stream>>>(xbuf, Wo, bo, (float*)d_out, 0);
}

// Round 2
// 593.908 us; speedup vs baseline: 2.8101x; 2.8101x over previous
//
#include <hip/hip_runtime.h>
#include <hip/hip_bf16.h>
#include <math.h>

// Problem constants
#define Bc  32
#define Nn  512
#define Dd  256
#define Hh  8
#define HDd 32
#define Ee  16384
#define KT  128   // attention k-tile

typedef __attribute__((ext_vector_type(8))) short bf16x8;
typedef __attribute__((ext_vector_type(4))) float f32x4;

__device__ inline ushort f2bf(float x){
  union { float f; unsigned u; } v; v.f = x;
  unsigned r = (v.u + 0x7fff + ((v.u >> 16) & 1)) >> 16;   // RNE
  return (ushort)r;
}

// ---------------- graph prep ----------------

__global__ __launch_bounds__(256) void k_init(int* count){
  int i = blockIdx.x*256 + threadIdx.x;
  if (i < Nn) count[i] = 0;
}

__global__ __launch_bounds__(256) void k_count(const int* __restrict__ ei, int* __restrict__ count){
  int e = blockIdx.x*256 + threadIdx.x;
  if (e < Ee){
    int d = ei[Ee + e];        // dst row of edge_index [2,E]
    atomicAdd(&count[d], 1);
  }
}

__global__ __launch_bounds__(512) void k_scan(const int* __restrict__ count, float* __restrict__ dinv,
                                              int* __restrict__ row_start, int* __restrict__ cursor){
  __shared__ int tmp[512];
  int t = threadIdx.x;
  int c = count[t];
  tmp[t] = c;
  dinv[t] = 1.0f / sqrtf(1.0f + (float)c);   // deg includes self-loop
  __syncthreads();
  for (int off = 1; off < 512; off <<= 1){
    int add = (t >= off) ? tmp[t-off] : 0;
    __syncthreads();
    tmp[t] += add;
    __syncthreads();
  }
  int excl = tmp[t] - c;
  row_start[t] = excl;
  cursor[t]    = excl;
  if (t == 511) row_start[512] = tmp[511];
}

__global__ __launch_bounds__(256) void k_fill(const int* __restrict__ ei, const float* __restrict__ dinv,
                                              int* __restrict__ cursor, int* __restrict__ csr_src,
                                              float* __restrict__ csr_w){
  int e = blockIdx.x*256 + threadIdx.x;
  if (e < Ee){
    int s = ei[e];
    int d = ei[Ee + e];
    int pos = atomicAdd(&cursor[d], 1);
    csr_src[pos] = s;
    csr_w[pos]   = dinv[s] * dinv[d];
  }
}

// ---------------- GCN aggregation ----------------
__global__ __launch_bounds__(256) void k_agg(const float* __restrict__ x, const float* __restrict__ dinv,
                                             const int* __restrict__ row_start, const int* __restrict__ csr_src,
                                             const float* __restrict__ csr_w, float* __restrict__ out){
  int bn = blockIdx.x;          // b*512 + n
  int n  = bn & (Nn-1);
  int b  = bn >> 9;
  int d  = threadIdx.x;         // 0..255
  const float* xb = x + (size_t)b*Nn*Dd;
  float acc = dinv[n]*dinv[n] * xb[n*Dd + d];
  int s0 = row_start[n], s1 = row_start[n+1];
  for (int j = s0; j < s1; j++){
    int   s = csr_src[j];
    float w = csr_w[j];
    acc += w * xb[s*Dd + d];
  }
  out[(size_t)bn*Dd + d] = acc;
}

// ---------------- GEMM: C[M=16384 x 256] = A * W + bias
// mode 0: fp32 flat [M,256]; mode 1: bf16 head layout [B,H,N,HD]
__global__ __launch_bounds__(256) void k_gemm(const float* __restrict__ A, const float* __restrict__ W,
                                              const float* __restrict__ bias, void* __restrict__ outp,
                                              int mode){
  __shared__ float As[16][65];   // As[k][m]
  __shared__ float Bs[16][65];   // Bs[k][n]
  int t  = threadIdx.x;
  int m0 = blockIdx.x * 64;
  int n0 = blockIdx.y * 64;
  int ty = t >> 4, tx = t & 15;
  float acc[4][4] = {};
  for (int k0 = 0; k0 < Dd; k0 += 16){
    #pragma unroll
    for (int r = 0; r < 4; r++){
      int idx = t + r*256;
      int mm = idx >> 4, kk = idx & 15;
      As[kk][mm] = A[(size_t)(m0+mm)*Dd + k0 + kk];
    }
    #pragma unroll
    for (int r = 0; r < 4; r++){
      int idx = t + r*256;
      int kk = idx >> 6, nn = idx & 63;
      Bs[kk][nn] = W[(size_t)(k0+kk)*Dd + n0 + nn];
    }
    __syncthreads();
    #pragma unroll
    for (int kk = 0; kk < 16; kk++){
      float a[4], bb[4];
      #pragma unroll
      for (int u = 0; u < 4; u++) a[u]  = As[kk][ty*4+u];
      #pragma unroll
      for (int v = 0; v < 4; v++) bb[v] = Bs[kk][tx*4+v];
      #pragma unroll
      for (int u = 0; u < 4; u++)
        #pragma unroll
        for (int v = 0; v < 4; v++)
          acc[u][v] += a[u]*bb[v];
    }
    __syncthreads();
  }
  float* outf = (float*)outp;
  ushort* outb = (ushort*)outp;
  #pragma unroll
  for (int u = 0; u < 4; u++){
    int m = m0 + ty*4 + u;
    int b = m >> 9, n = m & (Nn-1);
    #pragma unroll
    for (int v = 0; v < 4; v++){
      int col = n0 + tx*4 + v;
      float val = acc[u][v] + bias[col];
      if (mode == 0){
        outf[(size_t)m*Dd + col] = val;
      } else {
        int h = col >> 5, hd = col & 31;
        outb[((size_t)(b*Hh + h)*Nn + n)*HDd + hd] = f2bf(val);
      }
    }
  }
}

// ---------------- MFMA attention ----------------
// block = one (b,h), 64 q-rows (4 waves x 16). K-tiles of 128 staged in LDS (bf16).
// Softmax without max-subtraction (scores O(1)); masked entries get exp=0.
// P kept fp32 in wave-private LDS; cvt to bf16 A-frags for PV MFMA.
__global__ __launch_bounds__(256) void k_attn(const ushort* __restrict__ Qg, const ushort* __restrict__ Kg,
                                              const ushort* __restrict__ Vg, const int* __restrict__ mask,
                                              float* __restrict__ xout){
  __shared__ ushort Ks[KT][40];        // K rows, padded to 80 B (2-way bank alias on frag reads = free)
  __shared__ ushort Vs[HDd][KT+8];     // V transposed [hd][k], padded to 272 B
  __shared__ float  Ps[4][16][KT+4];   // per-wave P fp32, stride 132 (2-way alias)

  int bx = blockIdx.x;
  int bh = bx >> 3;              // 0..255
  int qt = bx & 7;               // 64-row q tile
  int b = bh >> 3, h = bh & 7;
  int t = threadIdx.x;
  int wave = t >> 6, lane = t & 63;
  int g = lane >> 4, l16 = lane & 15;

  const ushort* Qp = Qg + (size_t)bh*Nn*HDd;
  const ushort* Kp = Kg + (size_t)bh*Nn*HDd;
  const ushort* Vp = Vg + (size_t)bh*Nn*HDd;

  int q0 = qt*64 + wave*16;

  // Q A-frag straight from global: lane = 16 contiguous bytes, wave = 1 KB contiguous
  bf16x8 qfrag = *(const bf16x8*)(Qp + (size_t)(q0 + l16)*HDd + g*8);

  f32x4 Ofrag[2] = {{0,0,0,0},{0,0,0,0}};
  float rsum[4] = {0,0,0,0};
  const float scale = 0.17677669529663687f;   // 1/sqrt(32)

  for (int kt = 0; kt < Nn; kt += KT){
    // stage K tile: 128 rows x 32 bf16, 16B units, coalesced
    for (int u = t; u < KT*4; u += 256){
      int r = u >> 2, c = u & 3;
      *(int4*)(&Ks[r][c*8]) = *(const int4*)(Kp + (size_t)(kt + r)*HDd + c*8);
    }
    // stage V tile transposed: read rows coalesced, scatter 2B into Vs[hd][k]
    for (int u = t; u < KT*4; u += 256){
      int r = u >> 2, c = u & 3;
      ushort tmp[8];
      *(int4*)tmp = *(const int4*)(Vp + (size_t)(kt + r)*HDd + c*8);
      #pragma unroll
      for (int j = 0; j < 8; j++) Vs[c*8 + j][r] = tmp[j];
    }
    __syncthreads();

    // QK^T: 8 MFMA -> S[16 x 128] in C layout (row=g*4+r, col=f*16+l16)
    f32x4 s[KT/16];
    #pragma unroll
    for (int f = 0; f < KT/16; f++){
      bf16x8 kfrag = *(const bf16x8*)(&Ks[f*16 + l16][g*8]);
      s[f] = __builtin_amdgcn_mfma_f32_16x16x32_bf16(qfrag, kfrag, (f32x4){0.f,0.f,0.f,0.f}, 0, 0, 0);
    }

    // mask + exp + row-sum accumulate, write P (fp32) to wave-private LDS
    #pragma unroll
    for (int f = 0; f < KT/16; f++){
      #pragma unroll
      for (int r = 0; r < 4; r++){
        int row = g*4 + r;
        int col = kt + f*16 + l16;
        int mv = mask[(size_t)(q0 + row)*Nn + col];
        float e = (mv != 0) ? __expf(s[f][r] * scale) : 0.0f;
        rsum[r] += e;
        Ps[wave][row][f*16 + l16] = e;
      }
    }
    // no barrier: Ps is wave-private; compiler orders LDS RAW via lgkmcnt

    // PV: O[16x32] += P[16x128] * V[128x32]; 4 k-steps x 2 n-tiles
    #pragma unroll
    for (int ks = 0; ks < KT/32; ks++){
      const float* pr = &Ps[wave][l16][ks*32 + g*8];
      bf16x8 af;
      #pragma unroll
      for (int j = 0; j < 8; j++) af[j] = (short)f2bf(pr[j]);
      #pragma unroll
      for (int nt = 0; nt < 2; nt++){
        bf16x8 vf = *(const bf16x8*)(&Vs[nt*16 + l16][ks*32 + g*8]);
        Ofrag[nt] = __builtin_amdgcn_mfma_f32_16x16x32_bf16(af, vf, Ofrag[nt], 0, 0, 0);
      }
    }
    __syncthreads();   // protect K/V staging for next tile
  }

  // reduce row sums across the 16-lane col group
  #pragma unroll
  for (int off = 1; off < 16; off <<= 1){
    #pragma unroll
    for (int r = 0; r < 4; r++)
      rsum[r] += __shfl_xor(rsum[r], off, 64);
  }

  // normalize + store O: xout[b, q0+row, h*32 + col] fp32
  #pragma unroll
  for (int nt = 0; nt < 2; nt++){
    #pragma unroll
    for (int r = 0; r < 4; r++){
      int row = q0 + g*4 + r;
      int col = h*HDd + nt*16 + l16;
      xout[((size_t)b*Nn + row)*Dd + col] = Ofrag[nt][r] / rsum[r];
    }
  }
}

// ---------------- launch ----------------
extern "C" void kernel_launch(void* const* d_in, const int* in_sizes, int n_in,
                              void* d_out, int out_size, void* d_ws, size_t ws_size,
                              hipStream_t stream){
  const float* query = (const float*)d_in[0];
  const float* key   = (const float*)d_in[1];
  const float* value = (const float*)d_in[2];
  const int*   ei    = (const int*)  d_in[3];
  const int*   mask  = (const int*)  d_in[4];
  const float* Wq = (const float*)d_in[5];
  const float* bq = (const float*)d_in[6];
  const float* Wk = (const float*)d_in[7];
  const float* bk = (const float*)d_in[8];
  const float* Wv = (const float*)d_in[9];
  const float* bv = (const float*)d_in[10];
  const float* Wo = (const float*)d_in[11];
  const float* bo = (const float*)d_in[12];

  char* ws = (char*)d_ws;
  size_t off = 0;
  auto alloc = [&](size_t bytes)->void*{
    void* p = ws + off;
    off = (off + bytes + 255) & ~(size_t)255;
    return p;
  };
  int*   count     = (int*)  alloc(Nn*4);
  int*   row_start = (int*)  alloc((Nn+1)*4);
  int*   cursor    = (int*)  alloc(Nn*4);
  float* dinv      = (float*)alloc(Nn*4);
  int*   csr_src   = (int*)  alloc((size_t)Ee*4);
  float* csr_w     = (float*)alloc((size_t)Ee*4);
  size_t tszf = (size_t)Bc*Nn*Dd*sizeof(float);
  size_t tszb = (size_t)Bc*Nn*Dd*sizeof(ushort);
  float*  aggbuf = (float*) alloc(tszf);
  ushort* Qh     = (ushort*)alloc(tszb);
  ushort* Kh     = (ushort*)alloc(tszb);
  ushort* Vh     = (ushort*)alloc(tszb);
  float*  xbuf   = (float*) alloc(tszf);

  k_init <<<2, 256, 0, stream>>>(count);
  k_count<<<Ee/256, 256, 0, stream>>>(ei, count);
  k_scan <<<1, 512, 0, stream>>>(count, dinv, row_start, cursor);
  k_fill <<<Ee/256, 256, 0, stream>>>(ei, dinv, cursor, csr_src, csr_w);

  dim3 gg(Bc*Nn/64, Dd/64);   // (256, 4)

  k_agg <<<Bc*Nn, 256, 0, stream>>>(query, dinv, row_start, csr_src, csr_w, aggbuf);
  k_gemm<<<gg, 256, 0, stream>>>(aggbuf, Wq, bq, (void*)Qh, 1);
  k_agg <<<Bc*Nn, 256, 0, stream>>>(key, dinv, row_start, csr_src, csr_w, aggbuf);
  k_gemm<<<gg, 256, 0, stream>>>(aggbuf, Wk, bk, (void*)Kh, 1);
  k_agg <<<Bc*Nn, 256, 0, stream>>>(value, dinv, row_start, csr_src, csr_w, aggbuf);
  k_gemm<<<gg, 256, 0, stream>>>(aggbuf, Wv, bv, (void*)Vh, 1);

  k_attn<<<Bc*Hh*8, 256, 0, stream>>>(Qh, Kh, Vh, mask, xbuf);

  k_gemm<<<gg, 256, 0, stream>>>(xbuf, Wo, bo, d_out, 0);
}

// Round 3
// 320.977 us; speedup vs baseline: 5.1995x; 1.8503x over previous
//
#include <hip/hip_runtime.h>
#include <hip/hip_bf16.h>
#include <math.h>

// Problem constants
#define Bc  32
#define Nn  512
#define Dd  256
#define Hh  8
#define HDd 32
#define Ee  16384
#define KT  128   // attention k-tile

typedef __attribute__((ext_vector_type(8))) short bf16x8;
typedef __attribute__((ext_vector_type(4))) float f32x4;

__device__ inline ushort f2bf(float x){
  union { float f; unsigned u; } v; v.f = x;
  unsigned r = (v.u + 0x7fff + ((v.u >> 16) & 1)) >> 16;   // RNE
  return (ushort)r;
}

// ---------------- graph prep ----------------

__global__ __launch_bounds__(256) void k_init(int* count){
  int i = blockIdx.x*256 + threadIdx.x;
  if (i < Nn) count[i] = 0;
}

__global__ __launch_bounds__(256) void k_count(const int* __restrict__ ei, int* __restrict__ count){
  int e = blockIdx.x*256 + threadIdx.x;
  if (e < Ee){
    int d = ei[Ee + e];        // dst row of edge_index [2,E]
    atomicAdd(&count[d], 1);
  }
}

__global__ __launch_bounds__(512) void k_scan(const int* __restrict__ count, float* __restrict__ dinv,
                                              int* __restrict__ row_start, int* __restrict__ cursor){
  __shared__ int tmp[512];
  int t = threadIdx.x;
  int c = count[t];
  tmp[t] = c;
  dinv[t] = 1.0f / sqrtf(1.0f + (float)c);   // deg includes self-loop
  __syncthreads();
  for (int off = 1; off < 512; off <<= 1){
    int add = (t >= off) ? tmp[t-off] : 0;
    __syncthreads();
    tmp[t] += add;
    __syncthreads();
  }
  int excl = tmp[t] - c;
  row_start[t] = excl;
  cursor[t]    = excl;
  if (t == 511) row_start[512] = tmp[511];
}

__global__ __launch_bounds__(256) void k_fill(const int* __restrict__ ei, const float* __restrict__ dinv,
                                              int* __restrict__ cursor, int* __restrict__ csr_src,
                                              float* __restrict__ csr_w){
  int e = blockIdx.x*256 + threadIdx.x;
  if (e < Ee){
    int s = ei[e];
    int d = ei[Ee + e];
    int pos = atomicAdd(&cursor[d], 1);
    csr_src[pos] = s;
    csr_w[pos]   = dinv[s] * dinv[d];
  }
}

// ---------------- merged GCN aggregation for q,k,v; bf16 output ----------------
// wave per row; lane holds float4 (256 cols = 64 lanes x 4). Edge loop unrolled x2
// -> 6 outstanding 1KB coalesced row loads per wave. XCD swizzle keeps a batch's
// blocks on one XCD (L2 working set ~4.5 MB < 4 MiB-ish, mostly resident).
__global__ __launch_bounds__(256) void k_agg3(const float* __restrict__ q, const float* __restrict__ k,
                                              const float* __restrict__ v, const float* __restrict__ dinv,
                                              const int* __restrict__ row_start, const int* __restrict__ csr_src,
                                              const float* __restrict__ csr_w,
                                              ushort* __restrict__ aq, ushort* __restrict__ ak,
                                              ushort* __restrict__ av){
  int vv  = blockIdx.x;          // 4096 blocks
  int xcd = vv & 7;
  int j5  = vv >> 3;             // 0..511
  int b   = xcd*4 + (j5 >> 7);   // 4 batches per XCD
  int n4  = j5 & 127;
  int t = threadIdx.x, wave = t >> 6, lane = t & 63;
  int n = n4*4 + wave;

  const float4* q4 = (const float4*)(q + (size_t)b*Nn*Dd);
  const float4* k4 = (const float4*)(k + (size_t)b*Nn*Dd);
  const float4* v4 = (const float4*)(v + (size_t)b*Nn*Dd);

  float dn = dinv[n];
  float w0 = dn*dn;
  float4 sq = q4[n*64 + lane];
  float4 sk = k4[n*64 + lane];
  float4 sv = v4[n*64 + lane];
  float4 Aq = { w0*sq.x, w0*sq.y, w0*sq.z, w0*sq.w };
  float4 Ak = { w0*sk.x, w0*sk.y, w0*sk.z, w0*sk.w };
  float4 Av = { w0*sv.x, w0*sv.y, w0*sv.z, w0*sv.w };

  int s0 = row_start[n], s1 = row_start[n+1];
  int j = s0;
  #define FMA4(D,W,S) D.x += (W)*(S).x; D.y += (W)*(S).y; D.z += (W)*(S).z; D.w += (W)*(S).w;
  for (; j + 2 <= s1; j += 2){
    int sa = csr_src[j],   sb = csr_src[j+1];
    float wa = csr_w[j],   wb = csr_w[j+1];
    float4 qa = q4[sa*64 + lane];
    float4 ka = k4[sa*64 + lane];
    float4 va = v4[sa*64 + lane];
    float4 qb = q4[sb*64 + lane];
    float4 kb = k4[sb*64 + lane];
    float4 vb = v4[sb*64 + lane];
    FMA4(Aq, wa, qa); FMA4(Ak, wa, ka); FMA4(Av, wa, va);
    FMA4(Aq, wb, qb); FMA4(Ak, wb, kb); FMA4(Av, wb, vb);
  }
  if (j < s1){
    int sa = csr_src[j];
    float wa = csr_w[j];
    float4 qa = q4[sa*64 + lane];
    float4 ka = k4[sa*64 + lane];
    float4 va = v4[sa*64 + lane];
    FMA4(Aq, wa, qa); FMA4(Ak, wa, ka); FMA4(Av, wa, va);
  }
  #undef FMA4

  size_t obase = ((size_t)b*Nn + n)*Dd + lane*4;
  ushort4 oq = { f2bf(Aq.x), f2bf(Aq.y), f2bf(Aq.z), f2bf(Aq.w) };
  ushort4 ok = { f2bf(Ak.x), f2bf(Ak.y), f2bf(Ak.z), f2bf(Ak.w) };
  ushort4 ov = { f2bf(Av.x), f2bf(Av.y), f2bf(Av.z), f2bf(Av.w) };
  *(ushort4*)(aq + obase) = oq;
  *(ushort4*)(ak + obase) = ok;
  *(ushort4*)(av + obase) = ov;
}

// ---------------- MFMA QKV projection: C[16384x256] = Abf16 * W + bias -> bf16 head layout
// grid (256, 4, 3); z selects (A,W,bias,out). 64x64 tile, 4 waves, K chunks of 32.
__global__ __launch_bounds__(256) void k_gemm_qkv(const ushort* __restrict__ aggQ, const ushort* __restrict__ aggK,
                                                  const ushort* __restrict__ aggV,
                                                  const float* __restrict__ Wq, const float* __restrict__ Wk,
                                                  const float* __restrict__ Wv,
                                                  const float* __restrict__ bq, const float* __restrict__ bk,
                                                  const float* __restrict__ bv,
                                                  ushort* __restrict__ Qh, ushort* __restrict__ Kh,
                                                  ushort* __restrict__ Vh){
  int z = blockIdx.z;
  const ushort* A   = (z == 0) ? aggQ : (z == 1) ? aggK : aggV;
  const float*  W   = (z == 0) ? Wq   : (z == 1) ? Wk   : Wv;
  const float*  bia = (z == 0) ? bq   : (z == 1) ? bk   : bv;
  ushort*       out = (z == 0) ? Qh   : (z == 1) ? Kh   : Vh;

  __shared__ ushort As[64][40];   // A rows (m) x k-slice 32, pad->80B stride
  __shared__ ushort Ws[64][40];   // W^T: [n][k]

  int t = threadIdx.x, wave = t >> 6, lane = t & 63;
  int g = lane >> 4, l16 = lane & 15;
  int m0 = blockIdx.x * 64, n0 = blockIdx.y * 64;

  f32x4 acc[4] = {{0,0,0,0},{0,0,0,0},{0,0,0,0},{0,0,0,0}};

  for (int k0 = 0; k0 < Dd; k0 += 32){
    // stage A tile: 64 rows x 32 bf16; thread loads 16B
    {
      int r = t >> 2, c = (t & 3) * 8;
      *(int4*)(&As[r][c]) = *(const int4*)(A + (size_t)(m0 + r)*Dd + k0 + c);
    }
    // stage W^T tile: read W[k0+kk][n0+nn..+8] fp32 coalesced, cvt, transpose into Ws[n][k]
    {
      int kk = t >> 3, nn = (t & 7) * 8;
      float tmp[8];
      *(float4*)(tmp)     = *(const float4*)(W + (size_t)(k0 + kk)*Dd + n0 + nn);
      *(float4*)(tmp + 4) = *(const float4*)(W + (size_t)(k0 + kk)*Dd + n0 + nn + 4);
      #pragma unroll
      for (int jj = 0; jj < 8; jj++) Ws[nn + jj][kk] = f2bf(tmp[jj]);
    }
    __syncthreads();

    bf16x8 af = *(const bf16x8*)(&As[wave*16 + l16][g*8]);
    #pragma unroll
    for (int nf = 0; nf < 4; nf++){
      bf16x8 bf = *(const bf16x8*)(&Ws[nf*16 + l16][g*8]);
      acc[nf] = __builtin_amdgcn_mfma_f32_16x16x32_bf16(af, bf, acc[nf], 0, 0, 0);
    }
    __syncthreads();
  }

  // epilogue: D row = m (a-rows), col = n (b-rows); row=g*4+r, col=l16 within frag
  #pragma unroll
  for (int nf = 0; nf < 4; nf++){
    #pragma unroll
    for (int r = 0; r < 4; r++){
      int m = m0 + wave*16 + g*4 + r;
      int n = n0 + nf*16 + l16;
      float val = acc[nf][r] + bia[n];
      int b = m >> 9, nn = m & (Nn-1);
      int h = n >> 5, hd = n & 31;
      out[((size_t)(b*Hh + h)*Nn + nn)*HDd + hd] = f2bf(val);
    }
  }
}

// ---------------- fp32 GEMM (output projection): C[16384x256] = A*W + bias ----------------
__global__ __launch_bounds__(256) void k_gemm(const float* __restrict__ A, const float* __restrict__ W,
                                              const float* __restrict__ bias, float* __restrict__ out){
  __shared__ float As[16][65];   // As[k][m]
  __shared__ float Bs[16][65];   // Bs[k][n]
  int t  = threadIdx.x;
  int m0 = blockIdx.x * 64;
  int n0 = blockIdx.y * 64;
  int ty = t >> 4, tx = t & 15;
  float acc[4][4] = {};
  for (int k0 = 0; k0 < Dd; k0 += 16){
    #pragma unroll
    for (int r = 0; r < 4; r++){
      int idx = t + r*256;
      int mm = idx >> 4, kk = idx & 15;
      As[kk][mm] = A[(size_t)(m0+mm)*Dd + k0 + kk];
    }
    #pragma unroll
    for (int r = 0; r < 4; r++){
      int idx = t + r*256;
      int kk = idx >> 6, nn = idx & 63;
      Bs[kk][nn] = W[(size_t)(k0+kk)*Dd + n0 + nn];
    }
    __syncthreads();
    #pragma unroll
    for (int kk = 0; kk < 16; kk++){
      float a[4], bb[4];
      #pragma unroll
      for (int u = 0; u < 4; u++) a[u]  = As[kk][ty*4+u];
      #pragma unroll
      for (int v = 0; v < 4; v++) bb[v] = Bs[kk][tx*4+v];
      #pragma unroll
      for (int u = 0; u < 4; u++)
        #pragma unroll
        for (int v = 0; v < 4; v++)
          acc[u][v] += a[u]*bb[v];
    }
    __syncthreads();
  }
  #pragma unroll
  for (int u = 0; u < 4; u++){
    int m = m0 + ty*4 + u;
    #pragma unroll
    for (int v = 0; v < 4; v++){
      int col = n0 + tx*4 + v;
      out[(size_t)m*Dd + col] = acc[u][v] + bias[col];
    }
  }
}

// ---------------- MFMA attention ----------------
__global__ __launch_bounds__(256) void k_attn(const ushort* __restrict__ Qg, const ushort* __restrict__ Kg,
                                              const ushort* __restrict__ Vg, const int* __restrict__ mask,
                                              float* __restrict__ xout){
  __shared__ ushort Ks[KT][40];        // K rows, padded (2-way bank alias on frag reads = free)
  __shared__ ushort Vs[HDd][KT+8];     // V transposed [hd][k]
  __shared__ float  Ps[4][16][KT+4];   // per-wave P fp32

  int bx = blockIdx.x;
  int bh = bx >> 3;              // 0..255
  int qt = bx & 7;               // 64-row q tile
  int b = bh >> 3, h = bh & 7;
  int t = threadIdx.x;
  int wave = t >> 6, lane = t & 63;
  int g = lane >> 4, l16 = lane & 15;

  const ushort* Qp = Qg + (size_t)bh*Nn*HDd;
  const ushort* Kp = Kg + (size_t)bh*Nn*HDd;
  const ushort* Vp = Vg + (size_t)bh*Nn*HDd;

  int q0 = qt*64 + wave*16;

  bf16x8 qfrag = *(const bf16x8*)(Qp + (size_t)(q0 + l16)*HDd + g*8);

  f32x4 Ofrag[2] = {{0,0,0,0},{0,0,0,0}};
  float rsum[4] = {0,0,0,0};
  const float scale = 0.17677669529663687f;   // 1/sqrt(32)

  for (int kt = 0; kt < Nn; kt += KT){
    for (int u = t; u < KT*4; u += 256){
      int r = u >> 2, c = u & 3;
      *(int4*)(&Ks[r][c*8]) = *(const int4*)(Kp + (size_t)(kt + r)*HDd + c*8);
    }
    for (int u = t; u < KT*4; u += 256){
      int r = u >> 2, c = u & 3;
      ushort tmp[8];
      *(int4*)tmp = *(const int4*)(Vp + (size_t)(kt + r)*HDd + c*8);
      #pragma unroll
      for (int j = 0; j < 8; j++) Vs[c*8 + j][r] = tmp[j];
    }
    __syncthreads();

    f32x4 s[KT/16];
    #pragma unroll
    for (int f = 0; f < KT/16; f++){
      bf16x8 kfrag = *(const bf16x8*)(&Ks[f*16 + l16][g*8]);
      s[f] = __builtin_amdgcn_mfma_f32_16x16x32_bf16(qfrag, kfrag, (f32x4){0.f,0.f,0.f,0.f}, 0, 0, 0);
    }

    #pragma unroll
    for (int f = 0; f < KT/16; f++){
      #pragma unroll
      for (int r = 0; r < 4; r++){
        int row = g*4 + r;
        int col = kt + f*16 + l16;
        int mv = mask[(size_t)(q0 + row)*Nn + col];
        float e = (mv != 0) ? __expf(s[f][r] * scale) : 0.0f;
        rsum[r] += e;
        Ps[wave][row][f*16 + l16] = e;
      }
    }
    // no barrier: Ps is wave-private

    #pragma unroll
    for (int ks = 0; ks < KT/32; ks++){
      const float* pr = &Ps[wave][l16][ks*32 + g*8];
      bf16x8 af;
      #pragma unroll
      for (int j = 0; j < 8; j++) af[j] = (short)f2bf(pr[j]);
      #pragma unroll
      for (int nt = 0; nt < 2; nt++){
        bf16x8 vf = *(const bf16x8*)(&Vs[nt*16 + l16][ks*32 + g*8]);
        Ofrag[nt] = __builtin_amdgcn_mfma_f32_16x16x32_bf16(af, vf, Ofrag[nt], 0, 0, 0);
      }
    }
    __syncthreads();   // protect K/V staging for next tile
  }

  #pragma unroll
  for (int off = 1; off < 16; off <<= 1){
    #pragma unroll
    for (int r = 0; r < 4; r++)
      rsum[r] += __shfl_xor(rsum[r], off, 64);
  }

  #pragma unroll
  for (int nt = 0; nt < 2; nt++){
    #pragma unroll
    for (int r = 0; r < 4; r++){
      int row = q0 + g*4 + r;
      int col = h*HDd + nt*16 + l16;
      xout[((size_t)b*Nn + row)*Dd + col] = Ofrag[nt][r] / rsum[r];
    }
  }
}

// ---------------- launch ----------------
extern "C" void kernel_launch(void* const* d_in, const int* in_sizes, int n_in,
                              void* d_out, int out_size, void* d_ws, size_t ws_size,
                              hipStream_t stream){
  const float* query = (const float*)d_in[0];
  const float* key   = (const float*)d_in[1];
  const float* value = (const float*)d_in[2];
  const int*   ei    = (const int*)  d_in[3];
  const int*   mask  = (const int*)  d_in[4];
  const float* Wq = (const float*)d_in[5];
  const float* bq = (const float*)d_in[6];
  const float* Wk = (const float*)d_in[7];
  const float* bk = (const float*)d_in[8];
  const float* Wv = (const float*)d_in[9];
  const float* bv = (const float*)d_in[10];
  const float* Wo = (const float*)d_in[11];
  const float* bo = (const float*)d_in[12];

  char* ws = (char*)d_ws;
  size_t off = 0;
  auto alloc = [&](size_t bytes)->void*{
    void* p = ws + off;
    off = (off + bytes + 255) & ~(size_t)255;
    return p;
  };
  int*   count     = (int*)  alloc(Nn*4);
  int*   row_start = (int*)  alloc((Nn+1)*4);
  int*   cursor    = (int*)  alloc(Nn*4);
  float* dinv      = (float*)alloc(Nn*4);
  int*   csr_src   = (int*)  alloc((size_t)Ee*4);
  float* csr_w     = (float*)alloc((size_t)Ee*4);
  size_t tszf = (size_t)Bc*Nn*Dd*sizeof(float);
  size_t tszb = (size_t)Bc*Nn*Dd*sizeof(ushort);
  ushort* aggQ = (ushort*)alloc(tszb);
  ushort* aggK = (ushort*)alloc(tszb);
  ushort* aggV = (ushort*)alloc(tszb);
  ushort* Qh   = (ushort*)alloc(tszb);
  ushort* Kh   = (ushort*)alloc(tszb);
  ushort* Vh   = (ushort*)alloc(tszb);
  float*  xbuf = (float*) alloc(tszf);

  k_init <<<2, 256, 0, stream>>>(count);
  k_count<<<Ee/256, 256, 0, stream>>>(ei, count);
  k_scan <<<1, 512, 0, stream>>>(count, dinv, row_start, cursor);
  k_fill <<<Ee/256, 256, 0, stream>>>(ei, dinv, cursor, csr_src, csr_w);

  k_agg3<<<Bc*Nn/4, 256, 0, stream>>>(query, key, value, dinv, row_start, csr_src, csr_w,
                                      aggQ, aggK, aggV);

  dim3 gq(Bc*Nn/64, Dd/64, 3);   // (256, 4, 3)
  k_gemm_qkv<<<gq, 256, 0, stream>>>(aggQ, aggK, aggV, Wq, Wk, Wv, bq, bk, bv, Qh, Kh, Vh);

  k_attn<<<Bc*Hh*8, 256, 0, stream>>>(Qh, Kh, Vh, mask, xbuf);

  dim3 gg(Bc*Nn/64, Dd/64);      // (256, 4)
  k_gemm<<<gg, 256, 0, stream>>>(xbuf, Wo, bo, (float*)d_out);
}

// Round 4
// 249.739 us; speedup vs baseline: 6.6827x; 1.2853x over previous
//
#include <hip/hip_runtime.h>
#include <hip/hip_bf16.h>
#include <math.h>

// Problem constants
#define Bc  32
#define Nn  512
#define Dd  256
#define Hh  8
#define HDd 32
#define Ee  16384
#define KT  128   // attention k-tile

typedef __attribute__((ext_vector_type(8))) short bf16x8;
typedef __attribute__((ext_vector_type(4))) float f32x4;

__device__ inline ushort f2bf(float x){
  union { float f; unsigned u; } v; v.f = x;
  return (ushort)((v.u + 0x7fff + ((v.u >> 16) & 1)) >> 16);   // RNE
}
__device__ inline float bf2f(ushort h){
  union { unsigned u; float f; } v; v.u = ((unsigned)h) << 16; return v.f;
}

// ---------------- graph prep: dense normalized adjacency ----------------

__global__ __launch_bounds__(256) void k_count(const int* __restrict__ ei, int* __restrict__ count){
  int e = blockIdx.x*256 + threadIdx.x;
  if (e < Ee) atomicAdd(&count[ei[Ee + e]], 1);
}

__global__ __launch_bounds__(512) void k_dinv(const int* __restrict__ count, float* __restrict__ dinv){
  int t = threadIdx.x;
  dinv[t] = rsqrtf(1.0f + (float)count[t]);   // deg includes self-loop
}

__global__ __launch_bounds__(256) void k_scatter(const int* __restrict__ ei, const float* __restrict__ dinv,
                                                 float* __restrict__ S){
  int e = blockIdx.x*256 + threadIdx.x;
  if (e < Ee){
    int s = ei[e], d = ei[Ee + e];
    atomicAdd(&S[d*Nn + s], dinv[s]*dinv[d]);   // duplicates accumulate, matches ref
  }
}

// add self-loop diagonal, convert to bf16
__global__ __launch_bounds__(256) void k_sbf(const float* __restrict__ S, const float* __restrict__ dinv,
                                             ushort* __restrict__ Sb){
  int base = (blockIdx.x*256 + threadIdx.x)*4;
  #pragma unroll
  for (int j = 0; j < 4; j++){
    int i = base + j;
    int d = i >> 9, s = i & (Nn-1);
    float v = S[i] + ((d == s) ? dinv[d]*dinv[d] : 0.0f);
    Sb[i] = f2bf(v);
  }
}

// ---------------- W transpose+convert: Wt[n][k] bf16; Wo split hi/lo ----------------
__global__ __launch_bounds__(256) void k_wt(const float* __restrict__ Wq, const float* __restrict__ Wk,
                                            const float* __restrict__ Wv, const float* __restrict__ Wo,
                                            ushort* __restrict__ Wtq, ushort* __restrict__ Wtk,
                                            ushort* __restrict__ Wtv, ushort* __restrict__ Wto_h,
                                            ushort* __restrict__ Wto_l){
  __shared__ float Ls[64][65];
  int mat = blockIdx.z;
  const float* Wsrc = (mat==0)?Wq:(mat==1)?Wk:(mat==2)?Wv:Wo;
  int k0 = blockIdx.x*64, n0 = blockIdx.y*64;
  int t = threadIdx.x;
  {
    int r = t >> 2, c4 = (t & 3)*16;
    #pragma unroll
    for (int j = 0; j < 16; j += 4)
      *(float4*)&Ls[r][c4+j] = *(const float4*)(Wsrc + (size_t)(k0+r)*Dd + n0 + c4 + j);
  }
  __syncthreads();
  int nr = t >> 2, kc = (t & 3)*16;
  ushort hb[16], lb[16];
  #pragma unroll
  for (int j = 0; j < 16; j++){
    float w = Ls[kc+j][nr];
    ushort hh = f2bf(w);
    hb[j] = hh;
    lb[j] = f2bf(w - bf2f(hh));
  }
  size_t dst = (size_t)(n0+nr)*Dd + k0 + kc;
  if (mat < 3){
    ushort* Wt = (mat==0)?Wtq:(mat==1)?Wtk:Wtv;
    *(int4*)(Wt + dst)     = ((int4*)hb)[0];
    *(int4*)(Wt + dst + 8) = ((int4*)hb)[1];
  } else {
    *(int4*)(Wto_h + dst)     = ((int4*)hb)[0];
    *(int4*)(Wto_h + dst + 8) = ((int4*)hb)[1];
    *(int4*)(Wto_l + dst)     = ((int4*)lb)[0];
    *(int4*)(Wto_l + dst + 8) = ((int4*)lb)[1];
  }
}

// ---------------- k_proj: T = X@W (no bias), output transposed Tt[b][ch][node] bf16
// grid (8, 4, 96); z = which*32 + b. A staged fp32->bf16, B direct from Wt.
__global__ __launch_bounds__(256) void k_proj(const float* __restrict__ q, const float* __restrict__ k,
                                              const float* __restrict__ v,
                                              const ushort* __restrict__ Wtq, const ushort* __restrict__ Wtk,
                                              const ushort* __restrict__ Wtv,
                                              ushort* __restrict__ Ttq, ushort* __restrict__ Ttk,
                                              ushort* __restrict__ Ttv){
  int z = blockIdx.z;
  int which = z >> 5, b = z & 31;
  const float*  X  = (which==0)?q:(which==1)?k:v;
  const ushort* Wt = (which==0)?Wtq:(which==1)?Wtk:Wtv;
  ushort*       Tt = (which==0)?Ttq:(which==1)?Ttk:Ttv;

  __shared__ ushort As[64][40];
  __shared__ ushort Bs[64][40];
  __shared__ ushort Ts[64][72];

  int t = threadIdx.x, wave = t >> 6, lane = t & 63;
  int g = lane >> 4, l16 = lane & 15;
  int m0 = blockIdx.x*64, n0 = blockIdx.y*64;

  f32x4 acc[4] = {{0,0,0,0},{0,0,0,0},{0,0,0,0},{0,0,0,0}};
  int r = t >> 2, c = (t & 3)*8;

  for (int k0 = 0; k0 < Dd; k0 += 32){
    float tmpa[8];
    *(float4*)(tmpa)   = *(const float4*)(X + ((size_t)b*Nn + m0 + r)*Dd + k0 + c);
    *(float4*)(tmpa+4) = *(const float4*)(X + ((size_t)b*Nn + m0 + r)*Dd + k0 + c + 4);
    ushort ta[8];
    #pragma unroll
    for (int j = 0; j < 8; j++) ta[j] = f2bf(tmpa[j]);
    *(int4*)&As[r][c] = *(int4*)ta;
    *(int4*)&Bs[r][c] = *(const int4*)(Wt + (size_t)(n0 + r)*Dd + k0 + c);
    __syncthreads();
    bf16x8 af = *(const bf16x8*)&As[wave*16 + l16][g*8];
    #pragma unroll
    for (int nf = 0; nf < 4; nf++){
      bf16x8 bfr = *(const bf16x8*)&Bs[nf*16 + l16][g*8];
      acc[nf] = __builtin_amdgcn_mfma_f32_16x16x32_bf16(af, bfr, acc[nf], 0, 0, 0);
    }
    __syncthreads();
  }

  // transposed epilogue via LDS: Ts[n_local][m_local]
  #pragma unroll
  for (int nf = 0; nf < 4; nf++)
    #pragma unroll
    for (int rr = 0; rr < 4; rr++)
      Ts[nf*16 + l16][wave*16 + g*4 + rr] = f2bf(acc[nf][rr]);
  __syncthreads();
  int nr = t >> 2, mc = (t & 3)*16;
  size_t dst = ((size_t)b*Dd + n0 + nr)*Nn + m0 + mc;
  *(int4*)(Tt + dst)     = *(int4*)&Ts[nr][mc];
  *(int4*)(Tt + dst + 8) = *(int4*)&Ts[nr][mc + 8];
}

// ---------------- k_agge: QKV = S @ T + bias -> bf16 head layout [B,H,N,HD]
// grid (8, 4, 96); z = which*32 + b. Both operands direct 16B staging.
__global__ __launch_bounds__(256) void k_agge(const ushort* __restrict__ Sb,
                                              const ushort* __restrict__ Ttq, const ushort* __restrict__ Ttk,
                                              const ushort* __restrict__ Ttv,
                                              const float* __restrict__ bq, const float* __restrict__ bk,
                                              const float* __restrict__ bv,
                                              ushort* __restrict__ Qh, ushort* __restrict__ Kh,
                                              ushort* __restrict__ Vh){
  int z = blockIdx.z;
  int which = z >> 5, b = z & 31;
  const ushort* Tt  = (which==0)?Ttq:(which==1)?Ttk:Ttv;
  const float*  bia = (which==0)?bq:(which==1)?bk:bv;
  ushort*       out = (which==0)?Qh:(which==1)?Kh:Vh;

  __shared__ ushort As[64][40];
  __shared__ ushort Bs[64][40];

  int t = threadIdx.x, wave = t >> 6, lane = t & 63;
  int g = lane >> 4, l16 = lane & 15;
  int m0 = blockIdx.x*64, n0 = blockIdx.y*64;

  f32x4 acc[4] = {{0,0,0,0},{0,0,0,0},{0,0,0,0},{0,0,0,0}};
  int r = t >> 2, c = (t & 3)*8;

  for (int k0 = 0; k0 < Nn; k0 += 32){
    *(int4*)&As[r][c] = *(const int4*)(Sb + (size_t)(m0 + r)*Nn + k0 + c);
    *(int4*)&Bs[r][c] = *(const int4*)(Tt + ((size_t)b*Dd + n0 + r)*Nn + k0 + c);
    __syncthreads();
    bf16x8 af = *(const bf16x8*)&As[wave*16 + l16][g*8];
    #pragma unroll
    for (int nf = 0; nf < 4; nf++){
      bf16x8 bfr = *(const bf16x8*)&Bs[nf*16 + l16][g*8];
      acc[nf] = __builtin_amdgcn_mfma_f32_16x16x32_bf16(af, bfr, acc[nf], 0, 0, 0);
    }
    __syncthreads();
  }

  #pragma unroll
  for (int nf = 0; nf < 4; nf++){
    #pragma unroll
    for (int rr = 0; rr < 4; rr++){
      int m = m0 + wave*16 + g*4 + rr;     // node
      int n = n0 + nf*16 + l16;            // out channel
      float val = acc[nf][rr] + bia[n];
      int h = n >> 5, hd = n & 31;
      out[((size_t)(b*Hh + h)*Nn + m)*HDd + hd] = f2bf(val);
    }
  }
}

// ---------------- MFMA attention; epilogue emits x as hi/lo bf16 ----------------
__global__ __launch_bounds__(256) void k_attn(const ushort* __restrict__ Qg, const ushort* __restrict__ Kg,
                                              const ushort* __restrict__ Vg, const int* __restrict__ mask,
                                              ushort* __restrict__ xh, ushort* __restrict__ xl){
  __shared__ ushort Ks[KT][40];
  __shared__ ushort Vs[HDd][KT+8];
  __shared__ float  Ps[4][16][KT+4];

  int bx = blockIdx.x;
  int bh = bx >> 3;
  int qt = bx & 7;
  int b = bh >> 3, h = bh & 7;
  int t = threadIdx.x;
  int wave = t >> 6, lane = t & 63;
  int g = lane >> 4, l16 = lane & 15;

  const ushort* Qp = Qg + (size_t)bh*Nn*HDd;
  const ushort* Kp = Kg + (size_t)bh*Nn*HDd;
  const ushort* Vp = Vg + (size_t)bh*Nn*HDd;

  int q0 = qt*64 + wave*16;

  bf16x8 qfrag = *(const bf16x8*)(Qp + (size_t)(q0 + l16)*HDd + g*8);

  f32x4 Ofrag[2] = {{0,0,0,0},{0,0,0,0}};
  float rsum[4] = {0,0,0,0};
  const float scale = 0.17677669529663687f;   // 1/sqrt(32)

  for (int kt = 0; kt < Nn; kt += KT){
    for (int u = t; u < KT*4; u += 256){
      int r = u >> 2, c = u & 3;
      *(int4*)(&Ks[r][c*8]) = *(const int4*)(Kp + (size_t)(kt + r)*HDd + c*8);
    }
    for (int u = t; u < KT*4; u += 256){
      int r = u >> 2, c = u & 3;
      ushort tmp[8];
      *(int4*)tmp = *(const int4*)(Vp + (size_t)(kt + r)*HDd + c*8);
      #pragma unroll
      for (int j = 0; j < 8; j++) Vs[c*8 + j][r] = tmp[j];
    }
    __syncthreads();

    f32x4 s[KT/16];
    #pragma unroll
    for (int f = 0; f < KT/16; f++){
      bf16x8 kfrag = *(const bf16x8*)(&Ks[f*16 + l16][g*8]);
      s[f] = __builtin_amdgcn_mfma_f32_16x16x32_bf16(qfrag, kfrag, (f32x4){0.f,0.f,0.f,0.f}, 0, 0, 0);
    }

    #pragma unroll
    for (int f = 0; f < KT/16; f++){
      #pragma unroll
      for (int rr = 0; rr < 4; rr++){
        int row = g*4 + rr;
        int col = kt + f*16 + l16;
        int mv = mask[(size_t)(q0 + row)*Nn + col];
        float e = (mv != 0) ? __expf(s[f][rr] * scale) : 0.0f;
        rsum[rr] += e;
        Ps[wave][row][f*16 + l16] = e;
      }
    }
    // no barrier: Ps is wave-private

    #pragma unroll
    for (int ks = 0; ks < KT/32; ks++){
      const float* pr = &Ps[wave][l16][ks*32 + g*8];
      bf16x8 af;
      #pragma unroll
      for (int j = 0; j < 8; j++) af[j] = (short)f2bf(pr[j]);
      #pragma unroll
      for (int nt = 0; nt < 2; nt++){
        bf16x8 vf = *(const bf16x8*)(&Vs[nt*16 + l16][ks*32 + g*8]);
        Ofrag[nt] = __builtin_amdgcn_mfma_f32_16x16x32_bf16(af, vf, Ofrag[nt], 0, 0, 0);
      }
    }
    __syncthreads();
  }

  #pragma unroll
  for (int off = 1; off < 16; off <<= 1){
    #pragma unroll
    for (int rr = 0; rr < 4; rr++)
      rsum[rr] += __shfl_xor(rsum[rr], off, 64);
  }

  #pragma unroll
  for (int nt = 0; nt < 2; nt++){
    #pragma unroll
    for (int rr = 0; rr < 4; rr++){
      int row = q0 + g*4 + rr;
      int col = h*HDd + nt*16 + l16;
      float o = Ofrag[nt][rr] / rsum[rr];
      size_t idx = ((size_t)b*Nn + row)*Dd + col;
      ushort hh = f2bf(o);
      xh[idx] = hh;
      xl[idx] = f2bf(o - bf2f(hh));
    }
  }
}

// ---------------- out-projection: C = x@Wo + bo, split-bf16 3-chain (fp32 grade)
__global__ __launch_bounds__(256) void k_gemm_o(const ushort* __restrict__ xh, const ushort* __restrict__ xl,
                                                const ushort* __restrict__ Bh_, const ushort* __restrict__ Bl_,
                                                const float* __restrict__ bo, float* __restrict__ out){
  __shared__ ushort Ah[64][40];
  __shared__ ushort Al[64][40];
  __shared__ ushort Bh[64][40];
  __shared__ ushort Bl[64][40];

  int t = threadIdx.x, wave = t >> 6, lane = t & 63;
  int g = lane >> 4, l16 = lane & 15;
  int m0 = blockIdx.x*64, n0 = blockIdx.y*64;

  f32x4 acc[4] = {{0,0,0,0},{0,0,0,0},{0,0,0,0},{0,0,0,0}};
  int r = t >> 2, c = (t & 3)*8;

  for (int k0 = 0; k0 < Dd; k0 += 32){
    *(int4*)&Ah[r][c] = *(const int4*)(xh  + (size_t)(m0 + r)*Dd + k0 + c);
    *(int4*)&Al[r][c] = *(const int4*)(xl  + (size_t)(m0 + r)*Dd + k0 + c);
    *(int4*)&Bh[r][c] = *(const int4*)(Bh_ + (size_t)(n0 + r)*Dd + k0 + c);
    *(int4*)&Bl[r][c] = *(const int4*)(Bl_ + (size_t)(n0 + r)*Dd + k0 + c);
    __syncthreads();
    bf16x8 afh = *(const bf16x8*)&Ah[wave*16 + l16][g*8];
    bf16x8 afl = *(const bf16x8*)&Al[wave*16 + l16][g*8];
    #pragma unroll
    for (int nf = 0; nf < 4; nf++){
      bf16x8 bfh = *(const bf16x8*)&Bh[nf*16 + l16][g*8];
      bf16x8 bfl = *(const bf16x8*)&Bl[nf*16 + l16][g*8];
      acc[nf] = __builtin_amdgcn_mfma_f32_16x16x32_bf16(afh, bfh, acc[nf], 0, 0, 0);
      acc[nf] = __builtin_amdgcn_mfma_f32_16x16x32_bf16(afl, bfh, acc[nf], 0, 0, 0);
      acc[nf] = __builtin_amdgcn_mfma_f32_16x16x32_bf16(afh, bfl, acc[nf], 0, 0, 0);
    }
    __syncthreads();
  }

  #pragma unroll
  for (int nf = 0; nf < 4; nf++){
    #pragma unroll
    for (int rr = 0; rr < 4; rr++){
      int m = m0 + wave*16 + g*4 + rr;
      int n = n0 + nf*16 + l16;
      out[(size_t)m*Dd + n] = acc[nf][rr] + bo[n];
    }
  }
}

// ---------------- launch ----------------
extern "C" void kernel_launch(void* const* d_in, const int* in_sizes, int n_in,
                              void* d_out, int out_size, void* d_ws, size_t ws_size,
                              hipStream_t stream){
  const float* query = (const float*)d_in[0];
  const float* key   = (const float*)d_in[1];
  const float* value = (const float*)d_in[2];
  const int*   ei    = (const int*)  d_in[3];
  const int*   mask  = (const int*)  d_in[4];
  const float* Wq = (const float*)d_in[5];
  const float* bq = (const float*)d_in[6];
  const float* Wk = (const float*)d_in[7];
  const float* bk = (const float*)d_in[8];
  const float* Wv = (const float*)d_in[9];
  const float* bv = (const float*)d_in[10];
  const float* Wo = (const float*)d_in[11];
  const float* bo = (const float*)d_in[12];

  char* ws = (char*)d_ws;
  size_t off = 0;
  auto alloc = [&](size_t bytes)->void*{
    void* p = ws + off;
    off = (off + bytes + 255) & ~(size_t)255;
    return p;
  };
  int*    count  = (int*)   alloc(Nn*4);
  float*  dinv   = (float*) alloc(Nn*4);
  float*  S      = (float*) alloc((size_t)Nn*Nn*4);
  ushort* Sb     = (ushort*)alloc((size_t)Nn*Nn*2);
  ushort* Wtq    = (ushort*)alloc((size_t)Dd*Dd*2);
  ushort* Wtk    = (ushort*)alloc((size_t)Dd*Dd*2);
  ushort* Wtv    = (ushort*)alloc((size_t)Dd*Dd*2);
  ushort* Wto_h  = (ushort*)alloc((size_t)Dd*Dd*2);
  ushort* Wto_l  = (ushort*)alloc((size_t)Dd*Dd*2);
  size_t tszb = (size_t)Bc*Nn*Dd*sizeof(ushort);
  ushort* Ttq = (ushort*)alloc(tszb);
  ushort* Ttk = (ushort*)alloc(tszb);
  ushort* Ttv = (ushort*)alloc(tszb);
  ushort* Qh  = (ushort*)alloc(tszb);
  ushort* Kh  = (ushort*)alloc(tszb);
  ushort* Vh  = (ushort*)alloc(tszb);
  ushort* xh  = (ushort*)alloc(tszb);
  ushort* xl  = (ushort*)alloc(tszb);

  hipMemsetAsync(count, 0, Nn*4, stream);
  hipMemsetAsync(S, 0, (size_t)Nn*Nn*4, stream);

  k_count  <<<Ee/256, 256, 0, stream>>>(ei, count);
  k_dinv   <<<1, 512, 0, stream>>>(count, dinv);
  k_scatter<<<Ee/256, 256, 0, stream>>>(ei, dinv, S);
  k_sbf    <<<Nn*Nn/1024, 256, 0, stream>>>(S, dinv, Sb);

  dim3 gw(4, 4, 4);
  k_wt<<<gw, 256, 0, stream>>>(Wq, Wk, Wv, Wo, Wtq, Wtk, Wtv, Wto_h, Wto_l);

  dim3 gp(8, 4, 96);
  k_proj<<<gp, 256, 0, stream>>>(query, key, value, Wtq, Wtk, Wtv, Ttq, Ttk, Ttv);
  k_agge<<<gp, 256, 0, stream>>>(Sb, Ttq, Ttk, Ttv, bq, bk, bv, Qh, Kh, Vh);

  k_attn<<<Bc*Hh*8, 256, 0, stream>>>(Qh, Kh, Vh, mask, xh, xl);

  dim3 go(Bc*Nn/64, Dd/64);
  k_gemm_o<<<go, 256, 0, stream>>>(xh, xl, Wto_h, Wto_l, bo, (float*)d_out);
}

// Round 5
// 232.008 us; speedup vs baseline: 7.1934x; 1.0764x over previous
//
#include <hip/hip_runtime.h>
#include <hip/hip_bf16.h>
#include <math.h>

// Problem constants
#define Bc  32
#define Nn  512
#define Dd  256
#define Hh  8
#define HDd 32
#define Ee  16384
#define KT  128   // attention k-tile

typedef __attribute__((ext_vector_type(8))) short bf16x8;
typedef __attribute__((ext_vector_type(4))) float f32x4;

__device__ inline ushort f2bf(float x){
  union { float f; unsigned u; } v; v.f = x;
  return (ushort)((v.u + 0x7fff + ((v.u >> 16) & 1)) >> 16);   // RNE
}
__device__ inline float bf2f(ushort h){
  union { unsigned u; float f; } v; v.u = ((unsigned)h) << 16; return v.f;
}

// ---------------- graph prep: dense normalized adjacency ----------------

__global__ __launch_bounds__(256) void k_count(const int* __restrict__ ei, int* __restrict__ count){
  int e = blockIdx.x*256 + threadIdx.x;
  if (e < Ee) atomicAdd(&count[ei[Ee + e]], 1);
}

__global__ __launch_bounds__(256) void k_scatter(const int* __restrict__ ei, const int* __restrict__ count,
                                                 float* __restrict__ S){
  int e = blockIdx.x*256 + threadIdx.x;
  if (e < Ee){
    int s = ei[e], d = ei[Ee + e];
    float w = rsqrtf((1.0f + (float)count[s]) * (1.0f + (float)count[d]));
    atomicAdd(&S[d*Nn + s], w);   // duplicates accumulate, matches ref
  }
}

// add self-loop diagonal, convert to bf16
__global__ __launch_bounds__(256) void k_sbf(const float* __restrict__ S, const int* __restrict__ count,
                                             ushort* __restrict__ Sb){
  int base = (blockIdx.x*256 + threadIdx.x)*4;
  #pragma unroll
  for (int j = 0; j < 4; j++){
    int i = base + j;
    int d = i >> 9, s = i & (Nn-1);
    float v = S[i] + ((d == s) ? 1.0f/(1.0f + (float)count[d]) : 0.0f);
    Sb[i] = f2bf(v);
  }
}

// ---------------- W transpose+convert (z<4) + mask bit-pack (z==4) ----------------
__global__ __launch_bounds__(256) void k_wt(const float* __restrict__ Wq, const float* __restrict__ Wk,
                                            const float* __restrict__ Wv, const float* __restrict__ Wo,
                                            const int* __restrict__ mask,
                                            ushort* __restrict__ Wtq, ushort* __restrict__ Wtk,
                                            ushort* __restrict__ Wtv, ushort* __restrict__ Wto_h,
                                            ushort* __restrict__ Wto_l, ushort* __restrict__ Mbits){
  __shared__ float Ls[64][65];
  int mat = blockIdx.z;
  if (mat == 4){
    // pack mask into bits: Mbits[row*32 + w] bit i = mask[row*512 + w*16 + i]
    int bid = blockIdx.y*4 + blockIdx.x;        // 0..15
    int w0 = bid*1024 + threadIdx.x*4;
    #pragma unroll
    for (int j = 0; j < 4; j++){
      int w = w0 + j;
      int row = w >> 5, c0 = (w & 31) << 4;
      unsigned bits = 0;
      #pragma unroll
      for (int i = 0; i < 16; i++)
        bits |= (mask[(size_t)row*Nn + c0 + i] != 0 ? 1u : 0u) << i;
      Mbits[w] = (ushort)bits;
    }
    return;
  }
  const float* Wsrc = (mat==0)?Wq:(mat==1)?Wk:(mat==2)?Wv:Wo;
  int k0 = blockIdx.x*64, n0 = blockIdx.y*64;
  int t = threadIdx.x;
  {
    int r = t >> 2, c4 = (t & 3)*16;
    #pragma unroll
    for (int j = 0; j < 16; j += 4)
      *(float4*)&Ls[r][c4+j] = *(const float4*)(Wsrc + (size_t)(k0+r)*Dd + n0 + c4 + j);
  }
  __syncthreads();
  int nr = t >> 2, kc = (t & 3)*16;
  ushort hb[16], lb[16];
  #pragma unroll
  for (int j = 0; j < 16; j++){
    float w = Ls[kc+j][nr];
    ushort hh = f2bf(w);
    hb[j] = hh;
    lb[j] = f2bf(w - bf2f(hh));
  }
  size_t dst = (size_t)(n0+nr)*Dd + k0 + kc;
  if (mat < 3){
    ushort* Wt = (mat==0)?Wtq:(mat==1)?Wtk:Wtv;
    *(int4*)(Wt + dst)     = ((int4*)hb)[0];
    *(int4*)(Wt + dst + 8) = ((int4*)hb)[1];
  } else {
    *(int4*)(Wto_h + dst)     = ((int4*)hb)[0];
    *(int4*)(Wto_h + dst + 8) = ((int4*)hb)[1];
    *(int4*)(Wto_l + dst)     = ((int4*)lb)[0];
    *(int4*)(Wto_l + dst + 8) = ((int4*)lb)[1];
  }
}

// ---------------- k_proj: T = X@W (no bias), output transposed Tt[b][ch][node] bf16
__global__ __launch_bounds__(256) void k_proj(const float* __restrict__ q, const float* __restrict__ k,
                                              const float* __restrict__ v,
                                              const ushort* __restrict__ Wtq, const ushort* __restrict__ Wtk,
                                              const ushort* __restrict__ Wtv,
                                              ushort* __restrict__ Ttq, ushort* __restrict__ Ttk,
                                              ushort* __restrict__ Ttv){
  int z = blockIdx.z;
  int which = z >> 5, b = z & 31;
  const float*  X  = (which==0)?q:(which==1)?k:v;
  const ushort* Wt = (which==0)?Wtq:(which==1)?Wtk:Wtv;
  ushort*       Tt = (which==0)?Ttq:(which==1)?Ttk:Ttv;

  __shared__ ushort As[64][40];
  __shared__ ushort Bs[64][40];
  __shared__ ushort Ts[64][72];

  int t = threadIdx.x, wave = t >> 6, lane = t & 63;
  int g = lane >> 4, l16 = lane & 15;
  int m0 = blockIdx.x*64, n0 = blockIdx.y*64;

  f32x4 acc[4] = {{0,0,0,0},{0,0,0,0},{0,0,0,0},{0,0,0,0}};
  int r = t >> 2, c = (t & 3)*8;

  for (int k0 = 0; k0 < Dd; k0 += 32){
    float tmpa[8];
    *(float4*)(tmpa)   = *(const float4*)(X + ((size_t)b*Nn + m0 + r)*Dd + k0 + c);
    *(float4*)(tmpa+4) = *(const float4*)(X + ((size_t)b*Nn + m0 + r)*Dd + k0 + c + 4);
    ushort ta[8];
    #pragma unroll
    for (int j = 0; j < 8; j++) ta[j] = f2bf(tmpa[j]);
    *(int4*)&As[r][c] = *(int4*)ta;
    *(int4*)&Bs[r][c] = *(const int4*)(Wt + (size_t)(n0 + r)*Dd + k0 + c);
    __syncthreads();
    bf16x8 af = *(const bf16x8*)&As[wave*16 + l16][g*8];
    #pragma unroll
    for (int nf = 0; nf < 4; nf++){
      bf16x8 bfr = *(const bf16x8*)&Bs[nf*16 + l16][g*8];
      acc[nf] = __builtin_amdgcn_mfma_f32_16x16x32_bf16(af, bfr, acc[nf], 0, 0, 0);
    }
    __syncthreads();
  }

  #pragma unroll
  for (int nf = 0; nf < 4; nf++)
    #pragma unroll
    for (int rr = 0; rr < 4; rr++)
      Ts[nf*16 + l16][wave*16 + g*4 + rr] = f2bf(acc[nf][rr]);
  __syncthreads();
  int nr = t >> 2, mc = (t & 3)*16;
  size_t dst = ((size_t)b*Dd + n0 + nr)*Nn + m0 + mc;
  *(int4*)(Tt + dst)     = *(int4*)&Ts[nr][mc];
  *(int4*)(Tt + dst + 8) = *(int4*)&Ts[nr][mc + 8];
}

// ---------------- k_agge: QKV = S @ T + bias
// Q -> head layout, pre-scaled by 1/sqrt(32)*log2(e); K -> head layout; V -> transposed Vt[b][ch][node]
__global__ __launch_bounds__(256) void k_agge(const ushort* __restrict__ Sb,
                                              const ushort* __restrict__ Ttq, const ushort* __restrict__ Ttk,
                                              const ushort* __restrict__ Ttv,
                                              const float* __restrict__ bq, const float* __restrict__ bk,
                                              const float* __restrict__ bv,
                                              ushort* __restrict__ Qh, ushort* __restrict__ Kh,
                                              ushort* __restrict__ Vt){
  int z = blockIdx.z;
  int which = z >> 5, b = z & 31;
  const ushort* Tt  = (which==0)?Ttq:(which==1)?Ttk:Ttv;
  const float*  bia = (which==0)?bq:(which==1)?bk:bv;

  __shared__ ushort As[64][40];
  __shared__ ushort Bs[64][40];
  __shared__ ushort Ts[64][72];

  int t = threadIdx.x, wave = t >> 6, lane = t & 63;
  int g = lane >> 4, l16 = lane & 15;
  int m0 = blockIdx.x*64, n0 = blockIdx.y*64;

  f32x4 acc[4] = {{0,0,0,0},{0,0,0,0},{0,0,0,0},{0,0,0,0}};
  int r = t >> 2, c = (t & 3)*8;

  for (int k0 = 0; k0 < Nn; k0 += 32){
    *(int4*)&As[r][c] = *(const int4*)(Sb + (size_t)(m0 + r)*Nn + k0 + c);
    *(int4*)&Bs[r][c] = *(const int4*)(Tt + ((size_t)b*Dd + n0 + r)*Nn + k0 + c);
    __syncthreads();
    bf16x8 af = *(const bf16x8*)&As[wave*16 + l16][g*8];
    #pragma unroll
    for (int nf = 0; nf < 4; nf++){
      bf16x8 bfr = *(const bf16x8*)&Bs[nf*16 + l16][g*8];
      acc[nf] = __builtin_amdgcn_mfma_f32_16x16x32_bf16(af, bfr, acc[nf], 0, 0, 0);
    }
    __syncthreads();
  }

  const float qscale = 0.17677669529663687f * 1.4426950408889634f;  // 1/sqrt(32)*log2(e)

  if (which == 2){
    // V: bias then LDS-transpose -> Vt[(b*256 + channel)][node]
    #pragma unroll
    for (int nf = 0; nf < 4; nf++)
      #pragma unroll
      for (int rr = 0; rr < 4; rr++){
        int n = n0 + nf*16 + l16;
        Ts[nf*16 + l16][wave*16 + g*4 + rr] = f2bf(acc[nf][rr] + bia[n]);
      }
    __syncthreads();
    int nr = t >> 2, mc = (t & 3)*16;
    size_t dst = ((size_t)b*Dd + n0 + nr)*Nn + m0 + mc;
    *(int4*)(Vt + dst)     = *(int4*)&Ts[nr][mc];
    *(int4*)(Vt + dst + 8) = *(int4*)&Ts[nr][mc + 8];
  } else {
    ushort* out = (which==0) ? Qh : Kh;
    float sc = (which==0) ? qscale : 1.0f;
    #pragma unroll
    for (int nf = 0; nf < 4; nf++){
      #pragma unroll
      for (int rr = 0; rr < 4; rr++){
        int m = m0 + wave*16 + g*4 + rr;     // node
        int n = n0 + nf*16 + l16;            // out channel
        float val = (acc[nf][rr] + bia[n]) * sc;
        int h = n >> 5, hd = n & 31;
        out[((size_t)(b*Hh + h)*Nn + m)*HDd + hd] = f2bf(val);
      }
    }
  }
}

// ---------------- MFMA attention ----------------
// grid: bh = bx&255 (XCD-local KV reuse), qt = bx>>8. Mask via bitmask -> MFMA C-init.
// exp2 path (scale*log2e folded into Q). P bf16 in wave-private LDS. Row sums via ones-MFMA.
__global__ __launch_bounds__(256) void k_attn(const ushort* __restrict__ Qg, const ushort* __restrict__ Kg,
                                              const ushort* __restrict__ Vt, const ushort* __restrict__ Mbits,
                                              ushort* __restrict__ xh, ushort* __restrict__ xl){
  __shared__ ushort Ks[KT][40];        // K rows [k][hd]
  __shared__ ushort Vs[HDd][KT+8];     // V^T [hd][k], stride 136 (odd 4B-bank stride)
  __shared__ ushort Ps[4][16][KT+8];   // per-wave P bf16

  int bx = blockIdx.x;
  int bh = bx & 255;
  int qt = bx >> 8;
  int b = bh >> 3, h = bh & 7;
  int t = threadIdx.x, wave = t >> 6, lane = t & 63;
  int g = lane >> 4, l16 = lane & 15;

  const ushort* Qp = Qg + (size_t)bh*Nn*HDd;
  const ushort* Kp = Kg + (size_t)bh*Nn*HDd;
  const ushort* Vp = Vt + (size_t)bh*HDd*Nn;

  int q0 = qt*64 + wave*16;
  bf16x8 qfrag = *(const bf16x8*)(Qp + (size_t)(q0 + l16)*HDd + g*8);

  bf16x8 ones;
  #pragma unroll
  for (int j = 0; j < 8; j++) ones[j] = (short)0x3F80;   // 1.0 bf16

  f32x4 Ofrag[2] = {{0,0,0,0},{0,0,0,0}};
  f32x4 rs = {0,0,0,0};

  for (int kt = 0; kt < Nn; kt += KT){
    // stage K tile: 128 rows x 32 bf16, b128 coalesced
    #pragma unroll
    for (int i = 0; i < 2; i++){
      int id = t + i*256;
      int r = id >> 2, c = (id & 3)*8;
      *(int4*)&Ks[r][c] = *(const int4*)(Kp + (size_t)(kt + r)*HDd + c);
    }
    // stage V^T tile: 32 rows x 128, b128 coalesced (no scatter)
    #pragma unroll
    for (int i = 0; i < 2; i++){
      int id = t + i*256;
      int r = id >> 4, c = (id & 15)*8;
      *(int4*)&Vs[r][c] = *(const int4*)(Vp + (size_t)r*Nn + kt + c);
    }
    __syncthreads();

    // mask bits for my 4 rows, this 128-col tile: one int4 per row
    int4 mb4[4];
    #pragma unroll
    for (int r = 0; r < 4; r++)
      mb4[r] = *(const int4*)(Mbits + (size_t)(q0 + g*4 + r)*32 + (kt >> 4));

    #pragma unroll
    for (int f = 0; f < KT/16; f++){
      bf16x8 kfrag = *(const bf16x8*)&Ks[f*16 + l16][g*8];
      f32x4 ci;
      #pragma unroll
      for (int r = 0; r < 4; r++){
        unsigned w = ((const unsigned*)&mb4[r])[f >> 1];
        unsigned bit = (w >> ((f & 1)*16 + l16)) & 1u;
        ci[r] = bit ? 0.0f : -1e30f;
      }
      f32x4 s = __builtin_amdgcn_mfma_f32_16x16x32_bf16(qfrag, kfrag, ci, 0, 0, 0);
      #pragma unroll
      for (int r = 0; r < 4; r++){
        float e = __builtin_exp2f(s[r]);            // masked -> exp2(-1e30) = 0
        union { float f; unsigned u; } cv; cv.f = e;
        Ps[wave][g*4 + r][f*16 + l16] = (ushort)((cv.u + 0x8000u) >> 16);  // round-half-up bf16
      }
    }
    // no barrier: Ps is wave-private, lgkmcnt orders RAW

    #pragma unroll
    for (int ks = 0; ks < KT/32; ks++){
      bf16x8 af = *(const bf16x8*)&Ps[wave][l16][ks*32 + g*8];
      rs = __builtin_amdgcn_mfma_f32_16x16x32_bf16(af, ones, rs, 0, 0, 0);  // row sums
      #pragma unroll
      for (int nt = 0; nt < 2; nt++){
        bf16x8 vf = *(const bf16x8*)&Vs[nt*16 + l16][ks*32 + g*8];
        Ofrag[nt] = __builtin_amdgcn_mfma_f32_16x16x32_bf16(af, vf, Ofrag[nt], 0, 0, 0);
      }
    }
    __syncthreads();   // protect K/V staging for next tile
  }

  float inv[4];
  #pragma unroll
  for (int r = 0; r < 4; r++) inv[r] = 1.0f / rs[r];

  #pragma unroll
  for (int nt = 0; nt < 2; nt++){
    #pragma unroll
    for (int r = 0; r < 4; r++){
      int row = q0 + g*4 + r;
      int col = h*HDd + nt*16 + l16;
      float o = Ofrag[nt][r] * inv[r];
      size_t idx = ((size_t)b*Nn + row)*Dd + col;
      ushort hh = f2bf(o);
      xh[idx] = hh;
      xl[idx] = f2bf(o - bf2f(hh));
    }
  }
}

// ---------------- out-projection: C = x@Wo + bo, split-bf16 3-chain (fp32 grade)
__global__ __launch_bounds__(256) void k_gemm_o(const ushort* __restrict__ xh, const ushort* __restrict__ xl,
                                                const ushort* __restrict__ Bh_, const ushort* __restrict__ Bl_,
                                                const float* __restrict__ bo, float* __restrict__ out){
  __shared__ ushort Ah[64][40];
  __shared__ ushort Al[64][40];
  __shared__ ushort Bh[64][40];
  __shared__ ushort Bl[64][40];

  int t = threadIdx.x, wave = t >> 6, lane = t & 63;
  int g = lane >> 4, l16 = lane & 15;
  int m0 = blockIdx.x*64, n0 = blockIdx.y*64;

  f32x4 acc[4] = {{0,0,0,0},{0,0,0,0},{0,0,0,0},{0,0,0,0}};
  int r = t >> 2, c = (t & 3)*8;

  for (int k0 = 0; k0 < Dd; k0 += 32){
    *(int4*)&Ah[r][c] = *(const int4*)(xh  + (size_t)(m0 + r)*Dd + k0 + c);
    *(int4*)&Al[r][c] = *(const int4*)(xl  + (size_t)(m0 + r)*Dd + k0 + c);
    *(int4*)&Bh[r][c] = *(const int4*)(Bh_ + (size_t)(n0 + r)*Dd + k0 + c);
    *(int4*)&Bl[r][c] = *(const int4*)(Bl_ + (size_t)(n0 + r)*Dd + k0 + c);
    __syncthreads();
    bf16x8 afh = *(const bf16x8*)&Ah[wave*16 + l16][g*8];
    bf16x8 afl = *(const bf16x8*)&Al[wave*16 + l16][g*8];
    #pragma unroll
    for (int nf = 0; nf < 4; nf++){
      bf16x8 bfh = *(const bf16x8*)&Bh[nf*16 + l16][g*8];
      bf16x8 bfl = *(const bf16x8*)&Bl[nf*16 + l16][g*8];
      acc[nf] = __builtin_amdgcn_mfma_f32_16x16x32_bf16(afh, bfh, acc[nf], 0, 0, 0);
      acc[nf] = __builtin_amdgcn_mfma_f32_16x16x32_bf16(afl, bfh, acc[nf], 0, 0, 0);
      acc[nf] = __builtin_amdgcn_mfma_f32_16x16x32_bf16(afh, bfl, acc[nf], 0, 0, 0);
    }
    __syncthreads();
  }

  #pragma unroll
  for (int nf = 0; nf < 4; nf++){
    #pragma unroll
    for (int rr = 0; rr < 4; rr++){
      int m = m0 + wave*16 + g*4 + rr;
      int n = n0 + nf*16 + l16;
      out[(size_t)m*Dd + n] = acc[nf][rr] + bo[n];
    }
  }
}

// ---------------- launch ----------------
extern "C" void kernel_launch(void* const* d_in, const int* in_sizes, int n_in,
                              void* d_out, int out_size, void* d_ws, size_t ws_size,
                              hipStream_t stream){
  const float* query = (const float*)d_in[0];
  const float* key   = (const float*)d_in[1];
  const float* value = (const float*)d_in[2];
  const int*   ei    = (const int*)  d_in[3];
  const int*   mask  = (const int*)  d_in[4];
  const float* Wq = (const float*)d_in[5];
  const float* bq = (const float*)d_in[6];
  const float* Wk = (const float*)d_in[7];
  const float* bk = (const float*)d_in[8];
  const float* Wv = (const float*)d_in[9];
  const float* bv = (const float*)d_in[10];
  const float* Wo = (const float*)d_in[11];
  const float* bo = (const float*)d_in[12];

  char* ws = (char*)d_ws;
  size_t off = 0;
  auto alloc = [&](size_t bytes)->void*{
    void* p = ws + off;
    off = (off + bytes + 255) & ~(size_t)255;
    return p;
  };
  int*    count  = (int*)   alloc(Nn*4);
  float*  S      = (float*) alloc((size_t)Nn*Nn*4);
  ushort* Sb     = (ushort*)alloc((size_t)Nn*Nn*2);
  ushort* Mbits  = (ushort*)alloc((size_t)Nn*32*2);
  ushort* Wtq    = (ushort*)alloc((size_t)Dd*Dd*2);
  ushort* Wtk    = (ushort*)alloc((size_t)Dd*Dd*2);
  ushort* Wtv    = (ushort*)alloc((size_t)Dd*Dd*2);
  ushort* Wto_h  = (ushort*)alloc((size_t)Dd*Dd*2);
  ushort* Wto_l  = (ushort*)alloc((size_t)Dd*Dd*2);
  size_t tszb = (size_t)Bc*Nn*Dd*sizeof(ushort);
  ushort* Ttq = (ushort*)alloc(tszb);
  ushort* Ttk = (ushort*)alloc(tszb);
  ushort* Ttv = (ushort*)alloc(tszb);
  ushort* Qh  = (ushort*)alloc(tszb);
  ushort* Kh  = (ushort*)alloc(tszb);
  ushort* Vt  = (ushort*)alloc(tszb);
  ushort* xh  = (ushort*)alloc(tszb);
  ushort* xl  = (ushort*)alloc(tszb);

  hipMemsetAsync(count, 0, Nn*4, stream);
  hipMemsetAsync(S, 0, (size_t)Nn*Nn*4, stream);

  k_count  <<<Ee/256, 256, 0, stream>>>(ei, count);
  k_scatter<<<Ee/256, 256, 0, stream>>>(ei, count, S);
  k_sbf    <<<Nn*Nn/1024, 256, 0, stream>>>(S, count, Sb);

  dim3 gw(4, 4, 5);   // z=0..3: weight transpose; z=4: mask bit-pack
  k_wt<<<gw, 256, 0, stream>>>(Wq, Wk, Wv, Wo, mask, Wtq, Wtk, Wtv, Wto_h, Wto_l, Mbits);

  dim3 gp(8, 4, 96);
  k_proj<<<gp, 256, 0, stream>>>(query, key, value, Wtq, Wtk, Wtv, Ttq, Ttk, Ttv);
  k_agge<<<gp, 256, 0, stream>>>(Sb, Ttq, Ttk, Ttv, bq, bk, bv, Qh, Kh, Vt);

  k_attn<<<Bc*Hh*8, 256, 0, stream>>>(Qh, Kh, Vt, Mbits, xh, xl);

  dim3 go(Bc*Nn/64, Dd/64);
  k_gemm_o<<<go, 256, 0, stream>>>(xh, xl, Wto_h, Wto_l, bo, (float*)d_out);
}